// Round 24
// baseline (71.739 us; speedup 1.0000x reference)
//
#include <hip/hip_runtime.h>
#include <hip/hip_bf16.h>

typedef unsigned short u16;
typedef unsigned int u32;
typedef unsigned long long u64;
typedef short s16x8 __attribute__((ext_vector_type(8)));
typedef float f32x4 __attribute__((ext_vector_type(4)));
typedef float f32x16 __attribute__((ext_vector_type(16)));
typedef int i32x4 __attribute__((ext_vector_type(4)));

// fp32 -> bf16 round-to-nearest-even
static __device__ __forceinline__ u16 f2b(float f) {
    union { float f; unsigned u; } x; x.f = f;
    unsigned r = x.u + 0x7fffu + ((x.u >> 16) & 1u);
    return (u16)(r >> 16);
}

// pack two floats -> one u32 of 2 bf16 (low = a)
static __device__ __forceinline__ u32 pkbf2(float a, float b) {
    union { __hip_bfloat162 h; u32 u; } c;
    c.h = __float22bfloat162_rn(make_float2(a, b));
    return c.u;
}

static __device__ __forceinline__ f32x16 zero16() {
    f32x16 z;
#pragma unroll
    for (int i = 0; i < 16; i++) z[i] = 0.f;
    return z;
}

static __device__ __forceinline__ s16x8 mk8(u32 a, u32 b, u32 c, u32 d) {
    union { u32 u[4]; s16x8 v; } x;
    x.u[0] = a; x.u[1] = b; x.u[2] = c; x.u[3] = d;
    return x.v;
}

static __device__ __forceinline__ u32 sx32(u32 v) {
    return (u32)__shfl_xor((int)v, 32, 64);
}

// async global->LDS, 16B per lane; LDS dst = wave-uniform base + lane*16
static __device__ __forceinline__ void gll16(const u16* g, u16* l) {
    __builtin_amdgcn_global_load_lds(
        (const __attribute__((address_space(1))) u32*)g,
        (__attribute__((address_space(3))) u32*)l, 16, 0, 0);
}

// ---------------- pack: x + weights + bias (mask moved into proj GEMM) ------

__global__ __launch_bounds__(256)
void k_pack_all(const float* __restrict__ x,
                const float* __restrict__ Wq, const float* __restrict__ Wk,
                const float* __restrict__ Wv, const float* __restrict__ Wo,
                const float* __restrict__ bq, const float* __restrict__ bk,
                const float* __restrict__ bv, const float* __restrict__ bo,
                u16* __restrict__ xb, u16* __restrict__ WT, u16* __restrict__ WoT,
                float* __restrict__ bias) {
    int idx = blockIdx.x * 256 + threadIdx.x;
    if (idx < 524288) {
        int i = idx * 4;
        float4 v = *(const float4*)(x + i);
        ushort4 o;
        o.x = f2b(v.x); o.y = f2b(v.y); o.z = f2b(v.z); o.w = f2b(v.w);
        *(ushort4*)(xb + i) = o;
    } else if (idx < 1310720) {
        int t = idx - 524288;
        int z = t >> 18, r = t & 262143;
        const float* W = (z == 0) ? Wq : (z == 1) ? Wk : Wv;
        int n = r >> 9, d = r & 511;
        WT[t] = f2b(W[((n >> 6) * 512 + d) * 64 + (n & 63)]);
    } else if (idx < 1572864) {
        int r = idx - 1310720;
        int n = r >> 9, d = r & 511;
        WoT[r] = f2b(Wo[d * 512 + n]);
    } else if (idx < 1574912) {
        int i = idx - 1572864;
        float v;
        if (i < 512) v = bq[i];
        else if (i < 1024) v = bk[i - 512];
        else if (i < 1536) v = bv[i - 1024];
        else v = bo[i - 1536];
        bias[i] = v;
    }
}

// ---------------- GEMM: C = A(bf16) * BT^T + bias ----------------
// Double-buffered gll16 staging with counted vmcnt + raw barriers (no vmcnt(0)
// drain in the K-loop): compute(kt) -> lgkm+barrier (read release) -> issue
// stage(kt+2) -> vmcnt(6)+barrier (stage(kt+1) landed, per-wave count =>
// workgroup guarantee after barrier). LDS content identical to round 22.
// z==0 (Q) folds 1/8*log2(e); z==2 (V) writes transposed vt; z==3: mask pack.

template<int MF, bool F32OUT>
__global__ __launch_bounds__(256)
void k_gemm(const u16* __restrict__ A, const u16* __restrict__ BTbase,
            const float* __restrict__ biasBase,
            u16* __restrict__ Cb, u16* __restrict__ Vt, float* __restrict__ Cf,
            const int* __restrict__ mask, u32* __restrict__ mb) {
    const int BM = MF * 32;
    const int nblk = blockIdx.x, mblk = blockIdx.y, z = blockIdx.z;
    const int tid = threadIdx.x;

    if (!F32OUT && z == 3) {
        const int bi = mblk * 4 + nblk;
#pragma unroll
        for (int it = 0; it < 4; it++) {
            const int i2 = bi * 1024 + it * 256 + tid;
            const int* p = mask + (size_t)i2 * 32;
            unsigned wv2 = 0;
#pragma unroll
            for (int j = 0; j < 32; j += 4) {
                int4 v = *(const int4*)(p + j);
                wv2 |= ((unsigned)(v.x & 1) << j) | ((unsigned)(v.y & 1) << (j + 1)) |
                       ((unsigned)(v.z & 1) << (j + 2)) | ((unsigned)(v.w & 1) << (j + 3));
            }
            mb[i2] = wv2;
        }
        return;
    }

    const u16* BT = BTbase + (size_t)z * 262144;
    const float* bias = biasBase + z * 512;
    __shared__ __align__(16) u16 As[2][MF * 32 * 64];
    __shared__ __align__(16) u16 Bs[2][128 * 64];
    const int lane = tid & 63, wv = tid >> 6;
    const int lr = lane & 15, lg = lane >> 4;
    const int wr = (wv >> 1) * (MF * 16), wc = (wv & 1) * 64;
    // staging lane map (pre-swizzled source, linear LDS dst)
    const int lr8 = lane >> 3, lc8 = (lane & 7) ^ lr8;
    const u16* Ag = A + (size_t)(mblk * BM + wv * 8 + lr8) * 512 + lc8 * 8;
    const u16* Bg = BT + (size_t)(nblk * 128 + wv * 8 + lr8) * 512 + lc8 * 8;

    f32x4 acc[MF][4];
#pragma unroll
    for (int i = 0; i < MF; i++)
#pragma unroll
        for (int j = 0; j < 4; j++) acc[i][j] = (f32x4){0.f, 0.f, 0.f, 0.f};

    // prologue: stage kt=0 -> buf0, kt=1 -> buf1 (6 loads each per wave)
#pragma unroll
    for (int i = 0; i < MF; i++)
        gll16(Ag + (size_t)(i * 32) * 512, &As[0][(i * 32 + wv * 8) * 64]);
#pragma unroll
    for (int i = 0; i < 4; i++)
        gll16(Bg + (size_t)(i * 32) * 512, &Bs[0][(i * 32 + wv * 8) * 64]);
#pragma unroll
    for (int i = 0; i < MF; i++)
        gll16(Ag + (size_t)(i * 32) * 512 + 64, &As[1][(i * 32 + wv * 8) * 64]);
#pragma unroll
    for (int i = 0; i < 4; i++)
        gll16(Bg + (size_t)(i * 32) * 512 + 64, &Bs[1][(i * 32 + wv * 8) * 64]);
    asm volatile("s_waitcnt vmcnt(6)" ::: "memory");   // stage(0) landed
    __builtin_amdgcn_s_barrier();
    __builtin_amdgcn_sched_barrier(0);

    for (int kt = 0; kt < 8; kt++) {
        const int bo = kt & 1;
#pragma unroll
        for (int ks = 0; ks < 2; ks++) {
            s16x8 af[MF], bf[4];
#pragma unroll
            for (int mf = 0; mf < MF; mf++) {
                int r = wr + mf * 16 + lr;
                af[mf] = *(const s16x8*)&As[bo][r * 64 + ((ks * 32 + lg * 8) ^ ((r & 7) << 3))];
            }
#pragma unroll
            for (int nf = 0; nf < 4; nf++) {
                int r = wc + nf * 16 + lr;
                bf[nf] = *(const s16x8*)&Bs[bo][r * 64 + ((ks * 32 + lg * 8) ^ ((r & 7) << 3))];
            }
#pragma unroll
            for (int mf = 0; mf < MF; mf++)
#pragma unroll
                for (int nf = 0; nf < 4; nf++)
                    acc[mf][nf] = __builtin_amdgcn_mfma_f32_16x16x32_bf16(
                        af[mf], bf[nf], acc[mf][nf], 0, 0, 0);
        }
        // read-release: our ds_reads drained, then align all waves
        asm volatile("s_waitcnt lgkmcnt(0)" ::: "memory");
        __builtin_amdgcn_sched_barrier(0);
        __builtin_amdgcn_s_barrier();
        __builtin_amdgcn_sched_barrier(0);
        if (kt < 6) {
            const int koff = (kt + 2) * 64;
#pragma unroll
            for (int i = 0; i < MF; i++)
                gll16(Ag + (size_t)(i * 32) * 512 + koff, &As[bo][(i * 32 + wv * 8) * 64]);
#pragma unroll
            for (int i = 0; i < 4; i++)
                gll16(Bg + (size_t)(i * 32) * 512 + koff, &Bs[bo][(i * 32 + wv * 8) * 64]);
        }
        if (kt < 7) {
            if (kt < 6) asm volatile("s_waitcnt vmcnt(6)" ::: "memory");  // stage(kt+1) landed
            else        asm volatile("s_waitcnt vmcnt(0)" ::: "memory");  // stage(7) landed
            __builtin_amdgcn_s_barrier();
            __builtin_amdgcn_sched_barrier(0);
        }
    }
    const float qsc = (!F32OUT && z == 0) ? 0.18033688011112042f : 1.0f;
#pragma unroll
    for (int nf = 0; nf < 4; nf++) {
        int col = nblk * 128 + wc + nf * 16 + lr;
        float bval = bias[col];
#pragma unroll
        for (int mf = 0; mf < MF; mf++) {
            int row0 = mblk * BM + wr + mf * 16 + lg * 4;
            if (F32OUT) {
#pragma unroll
                for (int r = 0; r < 4; r++)
                    Cf[(size_t)(row0 + r) * 512 + col] = acc[mf][nf][r] + bval;
            } else if (z == 2) {
                ushort4 o;
                o.x = f2b(acc[mf][nf][0] + bval);
                o.y = f2b(acc[mf][nf][1] + bval);
                o.z = f2b(acc[mf][nf][2] + bval);
                o.w = f2b(acc[mf][nf][3] + bval);
                *(ushort4*)(Vt + (size_t)(row0 >> 11) * 1048576 +
                            (size_t)col * 2048 + (row0 & 2047)) = o;
            } else {
#pragma unroll
                for (int r = 0; r < 4; r++)
                    Cb[(size_t)z * 2097152 + (size_t)(row0 + r) * 512 + col] =
                        f2b((acc[mf][nf][r] + bval) * qsc);
            }
        }
    }
}

// ---------------- flash attention v12: QK-ahead + SPLIT counted waits -------
// grid (qt=32, h=8, b=2) = 512 blocks, 256 threads = 4 warps, 2 blocks/CU.

__global__ __launch_bounds__(256, 2)
void k_attn(const u16* __restrict__ qkv, const u16* __restrict__ vt,
            const u32* __restrict__ mb, u16* __restrict__ oc) {
    const int qt = blockIdx.x, h = blockIdx.y, b = blockIdx.z;
    const u16* Qb = qkv + (size_t)b * 1048576 + h * 64;
    const u16* Kb = Qb + 2097152;
    const u16* VtH = vt + (size_t)b * 1048576 + (size_t)h * 131072;

    __shared__ __align__(16) u16 SMEM[24576];   // 4 warps x 6144: K dbuf 4096 | V 2048
    __shared__ float Lbuf[4][64];

    const int tid = threadIdx.x;
    const int lane = tid & 63, w = tid >> 6;    // w = kv-quarter
    const int hi = lane >> 5, l31 = lane & 31;
    const int qrow = qt * 64 + l31;             // qg0; qg1 = +32

    // hoist ALL mask words: 16 per q-group, contiguous per lane
    const u32* mbl = mb + (size_t)(b * 2048 + qrow) * 64 + w * 16;
    const u32* mbh = mbl + 2048;
    u32 ML[16], MH[16];
#pragma unroll
    for (int i = 0; i < 4; i++) {
        uint4 a = *(const uint4*)(mbl + 4 * i);
        uint4 c = *(const uint4*)(mbh + 4 * i);
        ML[4 * i] = a.x; ML[4 * i + 1] = a.y; ML[4 * i + 2] = a.z; ML[4 * i + 3] = a.w;
        MH[4 * i] = c.x; MH[4 * i + 1] = c.y; MH[4 * i + 2] = c.z; MH[4 * i + 3] = c.w;
    }

    // Q fragments (B-operand) for both q-groups, pre-scaled by 1/8*log2e
    s16x8 qfl[4], qfh[4];
#pragma unroll
    for (int ks = 0; ks < 4; ks++) {
        qfl[ks] = *(const s16x8*)(Qb + (size_t)qrow * 512 + ks * 16 + hi * 8);
        qfh[ks] = *(const s16x8*)(Qb + (size_t)(qrow + 32) * 512 + ks * 16 + hi * 8);
    }

    // staging lane maps (pre-swizzled source, linear LDS dst)
    const int lr8 = lane >> 3, lc8 = (lane & 7) ^ lr8;                 // K: 8r x 8c(16B)
    const int vr16 = lane >> 2, vc4 = (lane & 3) ^ ((lane >> 3) & 3);  // V: 16r x 4c(16B)
    const int kv0 = w * 512;

    const u16* kptr = Kb + (size_t)(kv0 + lr8) * 512 + lc8 * 8;
    const u16* vptr = VtH + (size_t)vr16 * 2048 + kv0 + vc4 * 8;

    u16* wbase = &SMEM[w * 6144];  // K bufs at +0/+2048, V at +4096
    u16* Vq = wbase + 4096;

    const int kswz = (l31 & 7) << 3;
    const int vkey = (l31 >> 1) & 3;

    // prologue: K(0)->buf0, V(0), K(1)->buf1 (masks/qf older, drained first)
#pragma unroll
    for (int i = 0; i < 4; i++)
        gll16(kptr + (size_t)(i * 8) * 512, wbase + i * 512);
#pragma unroll
    for (int i = 0; i < 4; i++)
        gll16(vptr + (size_t)(i * 16) * 2048, Vq + i * 512);
#pragma unroll
    for (int i = 0; i < 4; i++)
        gll16(kptr + (size_t)(32 + i * 8) * 512, wbase + 2048 + i * 512);
    asm volatile("s_waitcnt vmcnt(8)" ::: "memory");   // K(0) landed; [V0,K1] in flight
    __builtin_amdgcn_sched_barrier(0);

    f32x16 aL0 = zero16(), aL1 = zero16(), aH0 = zero16(), aH1 = zero16();
    f32x4 lvl = (f32x4){0.f, 0.f, 0.f, 0.f}, lvh = (f32x4){0.f, 0.f, 0.f, 0.f};

    // QK(0)
    f32x16 sl = zero16(), sh = zero16();
    __builtin_amdgcn_s_setprio(1);
#pragma unroll
    for (int ks = 0; ks < 4; ks++) {
        s16x8 kf = *(const s16x8*)&wbase[l31 * 64 + ((ks * 16 + hi * 8) ^ kswz)];
        sl = __builtin_amdgcn_mfma_f32_32x32x16_bf16(kf, qfl[ks], sl, 0, 0, 0);
        sh = __builtin_amdgcn_mfma_f32_32x32x16_bf16(kf, qfh[ks], sh, 0, 0, 0);
    }
    __builtin_amdgcn_s_setprio(0);

#pragma unroll
    for (int t = 0; t < 16; t++) {
        // ---- top: issue K(t+2); drain ONLY K(t+1) ----
        if (t < 14) {
            const u16* kp = kptr + (size_t)((t + 2) * 32) * 512;
            u16* db = wbase + ((t & 1) << 11);
#pragma unroll
            for (int i = 0; i < 4; i++)
                gll16(kp + (size_t)(i * 8) * 512, db + i * 512);
            asm volatile("s_waitcnt vmcnt(8)" ::: "memory");   // keep [V(t),K(t+2)]
        } else if (t == 14) {
            asm volatile("s_waitcnt vmcnt(4)" ::: "memory");   // drain K(15), keep V(14)
        } else {
            asm volatile("s_waitcnt vmcnt(0)" ::: "memory");
        }
        __builtin_amdgcn_sched_barrier(0);

        // ---- QK(t+1) BEFORE softmax(t): MFMA latency hides under VALU ----
        f32x16 nl, nh;
        if (t < 15) {
            const u16* Kn = wbase + (((t + 1) & 1) << 11);
            nl = zero16(); nh = zero16();
#pragma unroll
            for (int ks = 0; ks < 4; ks++) {
                s16x8 kf = *(const s16x8*)&Kn[l31 * 64 + ((ks * 16 + hi * 8) ^ kswz)];
                nl = __builtin_amdgcn_mfma_f32_32x32x16_bf16(kf, qfl[ks], nl, 0, 0, 0);
                nh = __builtin_amdgcn_mfma_f32_32x32x16_bf16(kf, qfh[ks], nh, 0, 0, 0);
            }
        }

        // ---- fixed-max softmax + pack + half-exchange, q-group 0 ----
        s16x8 pal0, pal1, pah0, pah1;
        {
            const u32 mw = ML[t] >> (hi * 4);
            u32 pk[8];
#pragma unroll
            for (int g = 0; g < 8; g++) {
                const int p0 = ((2 * g) & 3) + 8 * (g >> 1);
                float a = ((mw >> p0) & 1u) ? 0.f : __builtin_amdgcn_exp2f(sl[2 * g]);
                float b2 = ((mw >> (p0 + 1)) & 1u) ? 0.f : __builtin_amdgcn_exp2f(sl[2 * g + 1]);
                lvl[(2 * g) & 3] += a;
                lvl[(2 * g + 1) & 3] += b2;
                pk[g] = pkbf2(a, b2);
            }
            u32 xa = sx32(hi ? pk[0] : pk[2]);
            u32 xb = sx32(hi ? pk[1] : pk[3]);
            u32 xc = sx32(hi ? pk[4] : pk[6]);
            u32 xd = sx32(hi ? pk[5] : pk[7]);
            pal0 = hi ? mk8(xa, xb, pk[2], pk[3]) : mk8(pk[0], pk[1], xa, xb);
            pal1 = hi ? mk8(xc, xd, pk[6], pk[7]) : mk8(pk[4], pk[5], xc, xd);
        }
        // ---- q-group 1 ----
        {
            const u32 mw = MH[t] >> (hi * 4);
            u32 pk[8];
#pragma unroll
            for (int g = 0; g < 8; g++) {
                const int p0 = ((2 * g) & 3) + 8 * (g >> 1);
                float a = ((mw >> p0) & 1u) ? 0.f : __builtin_amdgcn_exp2f(sh[2 * g]);
                float b2 = ((mw >> (p0 + 1)) & 1u) ? 0.f : __builtin_amdgcn_exp2f(sh[2 * g + 1]);
                lvh[(2 * g) & 3] += a;
                lvh[(2 * g + 1) & 3] += b2;
                pk[g] = pkbf2(a, b2);
            }
            u32 xa = sx32(hi ? pk[0] : pk[2]);
            u32 xb = sx32(hi ? pk[1] : pk[3]);
            u32 xc = sx32(hi ? pk[4] : pk[6]);
            u32 xd = sx32(hi ? pk[5] : pk[7]);
            pah0 = hi ? mk8(xa, xb, pk[2], pk[3]) : mk8(pk[0], pk[1], xa, xb);
            pah1 = hi ? mk8(xc, xd, pk[6], pk[7]) : mk8(pk[4], pk[5], xc, xd);
        }

        // ---- mid: drain V(t) just before PV ----
        if (t < 14) asm volatile("s_waitcnt vmcnt(4)" ::: "memory");
        else        asm volatile("s_waitcnt vmcnt(0)" ::: "memory");
        __builtin_amdgcn_sched_barrier(0);

        // ---- PV: bv read once, used for both q-groups ----
        __builtin_amdgcn_s_setprio(1);
#pragma unroll
        for (int ksg = 0; ksg < 2; ksg++) {
            const int off = ((ksg * 2 + hi) ^ vkey) << 3;
            s16x8 bv0 = *(const s16x8*)&Vq[l31 * 32 + off];
            s16x8 bv1 = *(const s16x8*)&Vq[(32 + l31) * 32 + off];
            s16x8 pl = ksg ? pal1 : pal0;
            s16x8 ph = ksg ? pah1 : pah0;
            aL0 = __builtin_amdgcn_mfma_f32_32x32x16_bf16(pl, bv0, aL0, 0, 0, 0);
            aL1 = __builtin_amdgcn_mfma_f32_32x32x16_bf16(pl, bv1, aL1, 0, 0, 0);
            aH0 = __builtin_amdgcn_mfma_f32_32x32x16_bf16(ph, bv0, aH0, 0, 0, 0);
            aH1 = __builtin_amdgcn_mfma_f32_32x32x16_bf16(ph, bv1, aH1, 0, 0, 0);
        }
        __builtin_amdgcn_s_setprio(0);
        __builtin_amdgcn_sched_barrier(0);

        // ---- end: issue V(t+1) into the SAME V buffer ----
        if (t < 15) {
            const u16* vp = vptr + (t + 1) * 32;
#pragma unroll
            for (int i = 0; i < 4; i++)
                gll16(vp + (size_t)(i * 16) * 2048, Vq + i * 512);
            sl = nl; sh = nh;
        }
    }

    // ---- per-q L across halves ----
    float Lsl = (lvl[0] + lvl[1]) + (lvl[2] + lvl[3]);
    Lsl += __shfl_xor(Lsl, 32, 64);
    float Lsh = (lvh[0] + lvh[1]) + (lvh[2] + lvh[3]);
    Lsh += __shfl_xor(Lsh, 32, 64);
    if (lane < 32) { Lbuf[w][l31] = Lsl; Lbuf[w][32 + l31] = Lsh; }

    // ---- two-pass 4-way merge (Obuf = 4 warps x 2048 floats = 32KB) ----
    float* Obuf = (float*)SMEM;
    const int lx = (lane & 7) * 4;
    const int ob = w * 2048 + lane * 32;
    const int eh = w & 1, gg = w >> 1;
    __syncthreads();

    // pass 1: q-group 0
#pragma unroll
    for (int g = 0; g < 4; g++) {
        *(f32x4*)&Obuf[ob + ((4 * g) ^ lx)] =
            (f32x4){aL0[4 * g], aL0[4 * g + 1], aL0[4 * g + 2], aL0[4 * g + 3]};
        *(f32x4*)&Obuf[ob + ((16 + 4 * g) ^ lx)] =
            (f32x4){aL1[4 * g], aL1[4 * g + 1], aL1[4 * g + 2], aL1[4 * g + 3]};
    }
    __syncthreads();
#pragma unroll
    for (int gi = 0; gi < 2; gi++) {
        const int g = gg * 2 + gi;
        const int off = (16 * eh + 4 * g) ^ lx;
        f32x4 s0 = *(const f32x4*)&Obuf[lane * 32 + off];
        f32x4 s1 = *(const f32x4*)&Obuf[2048 + lane * 32 + off];
        f32x4 s2 = *(const f32x4*)&Obuf[4096 + lane * 32 + off];
        f32x4 s3 = *(const f32x4*)&Obuf[6144 + lane * 32 + off];
        f32x4 sum = (s0 + s1) + (s2 + s3);
#pragma unroll
        for (int j = 0; j < 4; j++) {
            const int q = j + 4 * hi + 8 * g;
            float D = Lbuf[0][q] + Lbuf[1][q] + Lbuf[2][q] + Lbuf[3][q];
            const size_t orow = ((size_t)b * 2048 + qt * 64 + q) * 512 + h * 64 + eh * 32;
            oc[orow + l31] = f2b(sum[j] / D);
        }
    }
    __syncthreads();

    // pass 2: q-group 1
#pragma unroll
    for (int g = 0; g < 4; g++) {
        *(f32x4*)&Obuf[ob + ((4 * g) ^ lx)] =
            (f32x4){aH0[4 * g], aH0[4 * g + 1], aH0[4 * g + 2], aH0[4 * g + 3]};
        *(f32x4*)&Obuf[ob + ((16 + 4 * g) ^ lx)] =
            (f32x4){aH1[4 * g], aH1[4 * g + 1], aH1[4 * g + 2], aH1[4 * g + 3]};
    }
    __syncthreads();
#pragma unroll
    for (int gi = 0; gi < 2; gi++) {
        const int g = gg * 2 + gi;
        const int off = (16 * eh + 4 * g) ^ lx;
        f32x4 s0 = *(const f32x4*)&Obuf[lane * 32 + off];
        f32x4 s1 = *(const f32x4*)&Obuf[2048 + lane * 32 + off];
        f32x4 s2 = *(const f32x4*)&Obuf[4096 + lane * 32 + off];
        f32x4 s3 = *(const f32x4*)&Obuf[6144 + lane * 32 + off];
        f32x4 sum = (s0 + s1) + (s2 + s3);
#pragma unroll
        for (int j = 0; j < 4; j++) {
            const int q = j + 4 * hi + 8 * g;
            float D = Lbuf[0][32 + q] + Lbuf[1][32 + q] + Lbuf[2][32 + q] + Lbuf[3][32 + q];
            const size_t orow = ((size_t)b * 2048 + qt * 64 + 32 + q) * 512 + h * 64 + eh * 32;
            oc[orow + l31] = f2b(sum[j] / D);
        }
    }
}

// ---------------- launcher ----------------

extern "C" void kernel_launch(void* const* d_in, const int* in_sizes, int n_in,
                              void* d_out, int out_size, void* d_ws, size_t ws_size,
                              hipStream_t stream) {
    const float* x    = (const float*)d_in[0];
    const int*   mask = (const int*)d_in[1];
    const float* Wq   = (const float*)d_in[2];
    const float* bq   = (const float*)d_in[3];
    const float* Wk   = (const float*)d_in[4];
    const float* bk   = (const float*)d_in[5];
    const float* Wv   = (const float*)d_in[6];
    const float* bv   = (const float*)d_in[7];
    const float* Wo   = (const float*)d_in[8];
    const float* bo   = (const float*)d_in[9];

    u16* xb     = (u16*)d_ws;              // 2097152 bf16
    u16* WT     = xb + 2097152;            // 3*262144
    u16* WoT    = WT + 786432;             // 262144
    u16* qkv    = WoT + 262144;            // Q,K: 2*2097152
    u16* vtp    = qkv + 4194304;           // 2097152 (vt[b][he][s])
    u16* oc     = qkv + 6291456;           // 2097152
    float* bias = (float*)(oc + 2097152);  // 2048 floats
    u32* mbits  = (u32*)(bias + 2048);     // 262144 words (1 MB)

    k_pack_all<<<6152, 256, 0, stream>>>(x, Wq, Wk, Wv, Wo, bq, bk, bv, bo,
                                         xb, WT, WoT, bias);
    k_gemm<2, false><<<dim3(4, 64, 4), 256, 0, stream>>>(
        xb, WT, bias, qkv, vtp, nullptr, mask, mbits);
    k_attn<<<dim3(32, 8, 2), 256, 0, stream>>>(qkv, vtp, mbits, oc);
    k_gemm<1, true><<<dim3(4, 128, 1), 256, 0, stream>>>(
        oc, WoT, bias + 1536, nullptr, nullptr, (float*)d_out, nullptr, nullptr);
}

// Round 25
// 70.504 us; speedup vs baseline: 1.0175x; 1.0175x over previous
//
#include <hip/hip_runtime.h>
#include <hip/hip_bf16.h>

typedef unsigned short u16;
typedef unsigned int u32;
typedef unsigned long long u64;
typedef short s16x8 __attribute__((ext_vector_type(8)));
typedef float f32x4 __attribute__((ext_vector_type(4)));
typedef float f32x16 __attribute__((ext_vector_type(16)));
typedef int i32x4 __attribute__((ext_vector_type(4)));

// fp32 -> bf16 round-to-nearest-even
static __device__ __forceinline__ u16 f2b(float f) {
    union { float f; unsigned u; } x; x.f = f;
    unsigned r = x.u + 0x7fffu + ((x.u >> 16) & 1u);
    return (u16)(r >> 16);
}

// pack two floats -> one u32 of 2 bf16 (low = a)
static __device__ __forceinline__ u32 pkbf2(float a, float b) {
    union { __hip_bfloat162 h; u32 u; } c;
    c.h = __float22bfloat162_rn(make_float2(a, b));
    return c.u;
}

static __device__ __forceinline__ f32x16 zero16() {
    f32x16 z;
#pragma unroll
    for (int i = 0; i < 16; i++) z[i] = 0.f;
    return z;
}

static __device__ __forceinline__ s16x8 mk8(u32 a, u32 b, u32 c, u32 d) {
    union { u32 u[4]; s16x8 v; } x;
    x.u[0] = a; x.u[1] = b; x.u[2] = c; x.u[3] = d;
    return x.v;
}

static __device__ __forceinline__ u32 sx32(u32 v) {
    return (u32)__shfl_xor((int)v, 32, 64);
}

// async global->LDS, 16B per lane; LDS dst = wave-uniform base + lane*16
static __device__ __forceinline__ void gll16(const u16* g, u16* l) {
    __builtin_amdgcn_global_load_lds(
        (const __attribute__((address_space(1))) u32*)g,
        (__attribute__((address_space(3))) u32*)l, 16, 0, 0);
}

// ---------------- pack: x + weights + bias (mask moved into proj GEMM) ------

__global__ __launch_bounds__(256)
void k_pack_all(const float* __restrict__ x,
                const float* __restrict__ Wq, const float* __restrict__ Wk,
                const float* __restrict__ Wv, const float* __restrict__ Wo,
                const float* __restrict__ bq, const float* __restrict__ bk,
                const float* __restrict__ bv, const float* __restrict__ bo,
                u16* __restrict__ xb, u16* __restrict__ WT, u16* __restrict__ WoT,
                float* __restrict__ bias) {
    int idx = blockIdx.x * 256 + threadIdx.x;
    if (idx < 524288) {
        int i = idx * 4;
        float4 v = *(const float4*)(x + i);
        ushort4 o;
        o.x = f2b(v.x); o.y = f2b(v.y); o.z = f2b(v.z); o.w = f2b(v.w);
        *(ushort4*)(xb + i) = o;
    } else if (idx < 1310720) {
        int t = idx - 524288;
        int z = t >> 18, r = t & 262143;
        const float* W = (z == 0) ? Wq : (z == 1) ? Wk : Wv;
        int n = r >> 9, d = r & 511;
        WT[t] = f2b(W[((n >> 6) * 512 + d) * 64 + (n & 63)]);
    } else if (idx < 1572864) {
        int r = idx - 1310720;
        int n = r >> 9, d = r & 511;
        WoT[r] = f2b(Wo[d * 512 + n]);
    } else if (idx < 1574912) {
        int i = idx - 1572864;
        float v;
        if (i < 512) v = bq[i];
        else if (i < 1024) v = bk[i - 512];
        else if (i < 1536) v = bv[i - 1024];
        else v = bo[i - 1536];
        bias[i] = v;
    }
}

// ---------------- GEMM: C = A(bf16) * BT^T + bias ----------------
// Staging via global_load_lds (16B/lane, pre-swizzled source, linear LDS dst).
// Single-buffered, 2 barriers/K-step (round-22 proven: 4 blocks/CU TLP beats
// the deeper pipeline — r23 falsified the counted-vmcnt variant here).
// z==0 (Q) folds 1/8*log2(e); z==2 (V) writes transposed vt; z==3: mask pack.

template<int MF, bool F32OUT>
__global__ __launch_bounds__(256)
void k_gemm(const u16* __restrict__ A, const u16* __restrict__ BTbase,
            const float* __restrict__ biasBase,
            u16* __restrict__ Cb, u16* __restrict__ Vt, float* __restrict__ Cf,
            const int* __restrict__ mask, u32* __restrict__ mb) {
    const int BM = MF * 32;
    const int nblk = blockIdx.x, mblk = blockIdx.y, z = blockIdx.z;
    const int tid = threadIdx.x;

    if (!F32OUT && z == 3) {
        const int bi = mblk * 4 + nblk;
#pragma unroll
        for (int it = 0; it < 4; it++) {
            const int i2 = bi * 1024 + it * 256 + tid;
            const int* p = mask + (size_t)i2 * 32;
            unsigned wv2 = 0;
#pragma unroll
            for (int j = 0; j < 32; j += 4) {
                int4 v = *(const int4*)(p + j);
                wv2 |= ((unsigned)(v.x & 1) << j) | ((unsigned)(v.y & 1) << (j + 1)) |
                       ((unsigned)(v.z & 1) << (j + 2)) | ((unsigned)(v.w & 1) << (j + 3));
            }
            mb[i2] = wv2;
        }
        return;
    }

    const u16* BT = BTbase + (size_t)z * 262144;
    const float* bias = biasBase + z * 512;
    __shared__ __align__(16) u16 As[MF * 32 * 64];
    __shared__ __align__(16) u16 Bs[128 * 64];
    const int lane = tid & 63, wv = tid >> 6;
    const int lr = lane & 15, lg = lane >> 4;
    const int wr = (wv >> 1) * (MF * 16), wc = (wv & 1) * 64;
    // staging lane map (pre-swizzled source, linear LDS dst)
    const int lr8 = lane >> 3, lc8 = (lane & 7) ^ lr8;
    const u16* Ag = A + (size_t)(mblk * BM + wv * 8 + lr8) * 512 + lc8 * 8;
    const u16* Bg = BT + (size_t)(nblk * 128 + wv * 8 + lr8) * 512 + lc8 * 8;

    f32x4 acc[MF][4];
#pragma unroll
    for (int i = 0; i < MF; i++)
#pragma unroll
        for (int j = 0; j < 4; j++) acc[i][j] = (f32x4){0.f, 0.f, 0.f, 0.f};

    for (int kt = 0; kt < 8; kt++) {
        __syncthreads();
#pragma unroll
        for (int i = 0; i < MF; i++)
            gll16(Ag + (size_t)(i * 32) * 512 + kt * 64, &As[(i * 32 + wv * 8) * 64]);
#pragma unroll
        for (int i = 0; i < 4; i++)
            gll16(Bg + (size_t)(i * 32) * 512 + kt * 64, &Bs[(i * 32 + wv * 8) * 64]);
        __syncthreads();
#pragma unroll
        for (int ks = 0; ks < 2; ks++) {
            s16x8 af[MF], bf[4];
#pragma unroll
            for (int mf = 0; mf < MF; mf++) {
                int r = wr + mf * 16 + lr;
                af[mf] = *(const s16x8*)&As[r * 64 + ((ks * 32 + lg * 8) ^ ((r & 7) << 3))];
            }
#pragma unroll
            for (int nf = 0; nf < 4; nf++) {
                int r = wc + nf * 16 + lr;
                bf[nf] = *(const s16x8*)&Bs[r * 64 + ((ks * 32 + lg * 8) ^ ((r & 7) << 3))];
            }
#pragma unroll
            for (int mf = 0; mf < MF; mf++)
#pragma unroll
                for (int nf = 0; nf < 4; nf++)
                    acc[mf][nf] = __builtin_amdgcn_mfma_f32_16x16x32_bf16(
                        af[mf], bf[nf], acc[mf][nf], 0, 0, 0);
        }
    }
    const float qsc = (!F32OUT && z == 0) ? 0.18033688011112042f : 1.0f;
#pragma unroll
    for (int nf = 0; nf < 4; nf++) {
        int col = nblk * 128 + wc + nf * 16 + lr;
        float bval = bias[col];
#pragma unroll
        for (int mf = 0; mf < MF; mf++) {
            int row0 = mblk * BM + wr + mf * 16 + lg * 4;
            if (F32OUT) {
#pragma unroll
                for (int r = 0; r < 4; r++)
                    Cf[(size_t)(row0 + r) * 512 + col] = acc[mf][nf][r] + bval;
            } else if (z == 2) {
                ushort4 o;
                o.x = f2b(acc[mf][nf][0] + bval);
                o.y = f2b(acc[mf][nf][1] + bval);
                o.z = f2b(acc[mf][nf][2] + bval);
                o.w = f2b(acc[mf][nf][3] + bval);
                *(ushort4*)(Vt + (size_t)(row0 >> 11) * 1048576 +
                            (size_t)col * 2048 + (row0 & 2047)) = o;
            } else {
#pragma unroll
                for (int r = 0; r < 4; r++)
                    Cb[(size_t)z * 2097152 + (size_t)(row0 + r) * 512 + col] =
                        f2b((acc[mf][nf][r] + bval) * qsc);
            }
        }
    }
}

// ---------------- flash attention v12: QK-ahead + SPLIT counted waits -------
// grid (qt=32, h=8, b=2) = 512 blocks, 256 threads = 4 warps, 2 blocks/CU.

__global__ __launch_bounds__(256, 2)
void k_attn(const u16* __restrict__ qkv, const u16* __restrict__ vt,
            const u32* __restrict__ mb, u16* __restrict__ oc) {
    const int qt = blockIdx.x, h = blockIdx.y, b = blockIdx.z;
    const u16* Qb = qkv + (size_t)b * 1048576 + h * 64;
    const u16* Kb = Qb + 2097152;
    const u16* VtH = vt + (size_t)b * 1048576 + (size_t)h * 131072;

    __shared__ __align__(16) u16 SMEM[24576];   // 4 warps x 6144: K dbuf 4096 | V 2048
    __shared__ float Lbuf[4][64];

    const int tid = threadIdx.x;
    const int lane = tid & 63, w = tid >> 6;    // w = kv-quarter
    const int hi = lane >> 5, l31 = lane & 31;
    const int qrow = qt * 64 + l31;             // qg0; qg1 = +32

    // hoist ALL mask words: 16 per q-group, contiguous per lane
    const u32* mbl = mb + (size_t)(b * 2048 + qrow) * 64 + w * 16;
    const u32* mbh = mbl + 2048;
    u32 ML[16], MH[16];
#pragma unroll
    for (int i = 0; i < 4; i++) {
        uint4 a = *(const uint4*)(mbl + 4 * i);
        uint4 c = *(const uint4*)(mbh + 4 * i);
        ML[4 * i] = a.x; ML[4 * i + 1] = a.y; ML[4 * i + 2] = a.z; ML[4 * i + 3] = a.w;
        MH[4 * i] = c.x; MH[4 * i + 1] = c.y; MH[4 * i + 2] = c.z; MH[4 * i + 3] = c.w;
    }

    // Q fragments (B-operand) for both q-groups, pre-scaled by 1/8*log2e
    s16x8 qfl[4], qfh[4];
#pragma unroll
    for (int ks = 0; ks < 4; ks++) {
        qfl[ks] = *(const s16x8*)(Qb + (size_t)qrow * 512 + ks * 16 + hi * 8);
        qfh[ks] = *(const s16x8*)(Qb + (size_t)(qrow + 32) * 512 + ks * 16 + hi * 8);
    }

    // staging lane maps (pre-swizzled source, linear LDS dst)
    const int lr8 = lane >> 3, lc8 = (lane & 7) ^ lr8;                 // K: 8r x 8c(16B)
    const int vr16 = lane >> 2, vc4 = (lane & 3) ^ ((lane >> 3) & 3);  // V: 16r x 4c(16B)
    const int kv0 = w * 512;

    const u16* kptr = Kb + (size_t)(kv0 + lr8) * 512 + lc8 * 8;
    const u16* vptr = VtH + (size_t)vr16 * 2048 + kv0 + vc4 * 8;

    u16* wbase = &SMEM[w * 6144];  // K bufs at +0/+2048, V at +4096
    u16* Vq = wbase + 4096;

    const int kswz = (l31 & 7) << 3;
    const int vkey = (l31 >> 1) & 3;

    // prologue: K(0)->buf0, V(0), K(1)->buf1 (masks/qf older, drained first)
#pragma unroll
    for (int i = 0; i < 4; i++)
        gll16(kptr + (size_t)(i * 8) * 512, wbase + i * 512);
#pragma unroll
    for (int i = 0; i < 4; i++)
        gll16(vptr + (size_t)(i * 16) * 2048, Vq + i * 512);
#pragma unroll
    for (int i = 0; i < 4; i++)
        gll16(kptr + (size_t)(32 + i * 8) * 512, wbase + 2048 + i * 512);
    asm volatile("s_waitcnt vmcnt(8)" ::: "memory");   // K(0) landed; [V0,K1] in flight
    __builtin_amdgcn_sched_barrier(0);

    f32x16 aL0 = zero16(), aL1 = zero16(), aH0 = zero16(), aH1 = zero16();
    f32x4 lvl = (f32x4){0.f, 0.f, 0.f, 0.f}, lvh = (f32x4){0.f, 0.f, 0.f, 0.f};

    // QK(0)
    f32x16 sl = zero16(), sh = zero16();
    __builtin_amdgcn_s_setprio(1);
#pragma unroll
    for (int ks = 0; ks < 4; ks++) {
        s16x8 kf = *(const s16x8*)&wbase[l31 * 64 + ((ks * 16 + hi * 8) ^ kswz)];
        sl = __builtin_amdgcn_mfma_f32_32x32x16_bf16(kf, qfl[ks], sl, 0, 0, 0);
        sh = __builtin_amdgcn_mfma_f32_32x32x16_bf16(kf, qfh[ks], sh, 0, 0, 0);
    }
    __builtin_amdgcn_s_setprio(0);

#pragma unroll
    for (int t = 0; t < 16; t++) {
        // ---- top: issue K(t+2); drain ONLY K(t+1) ----
        if (t < 14) {
            const u16* kp = kptr + (size_t)((t + 2) * 32) * 512;
            u16* db = wbase + ((t & 1) << 11);
#pragma unroll
            for (int i = 0; i < 4; i++)
                gll16(kp + (size_t)(i * 8) * 512, db + i * 512);
            asm volatile("s_waitcnt vmcnt(8)" ::: "memory");   // keep [V(t),K(t+2)]
        } else if (t == 14) {
            asm volatile("s_waitcnt vmcnt(4)" ::: "memory");   // drain K(15), keep V(14)
        } else {
            asm volatile("s_waitcnt vmcnt(0)" ::: "memory");
        }
        __builtin_amdgcn_sched_barrier(0);

        // ---- QK(t+1) BEFORE softmax(t): MFMA latency hides under VALU ----
        f32x16 nl, nh;
        if (t < 15) {
            const u16* Kn = wbase + (((t + 1) & 1) << 11);
            nl = zero16(); nh = zero16();
#pragma unroll
            for (int ks = 0; ks < 4; ks++) {
                s16x8 kf = *(const s16x8*)&Kn[l31 * 64 + ((ks * 16 + hi * 8) ^ kswz)];
                nl = __builtin_amdgcn_mfma_f32_32x32x16_bf16(kf, qfl[ks], nl, 0, 0, 0);
                nh = __builtin_amdgcn_mfma_f32_32x32x16_bf16(kf, qfh[ks], nh, 0, 0, 0);
            }
        }

        // ---- fixed-max softmax + pack + half-exchange, q-group 0 ----
        s16x8 pal0, pal1, pah0, pah1;
        {
            const u32 mw = ML[t] >> (hi * 4);
            u32 pk[8];
#pragma unroll
            for (int g = 0; g < 8; g++) {
                const int p0 = ((2 * g) & 3) + 8 * (g >> 1);
                float a = ((mw >> p0) & 1u) ? 0.f : __builtin_amdgcn_exp2f(sl[2 * g]);
                float b2 = ((mw >> (p0 + 1)) & 1u) ? 0.f : __builtin_amdgcn_exp2f(sl[2 * g + 1]);
                lvl[(2 * g) & 3] += a;
                lvl[(2 * g + 1) & 3] += b2;
                pk[g] = pkbf2(a, b2);
            }
            u32 xa = sx32(hi ? pk[0] : pk[2]);
            u32 xb = sx32(hi ? pk[1] : pk[3]);
            u32 xc = sx32(hi ? pk[4] : pk[6]);
            u32 xd = sx32(hi ? pk[5] : pk[7]);
            pal0 = hi ? mk8(xa, xb, pk[2], pk[3]) : mk8(pk[0], pk[1], xa, xb);
            pal1 = hi ? mk8(xc, xd, pk[6], pk[7]) : mk8(pk[4], pk[5], xc, xd);
        }
        // ---- q-group 1 ----
        {
            const u32 mw = MH[t] >> (hi * 4);
            u32 pk[8];
#pragma unroll
            for (int g = 0; g < 8; g++) {
                const int p0 = ((2 * g) & 3) + 8 * (g >> 1);
                float a = ((mw >> p0) & 1u) ? 0.f : __builtin_amdgcn_exp2f(sh[2 * g]);
                float b2 = ((mw >> (p0 + 1)) & 1u) ? 0.f : __builtin_amdgcn_exp2f(sh[2 * g + 1]);
                lvh[(2 * g) & 3] += a;
                lvh[(2 * g + 1) & 3] += b2;
                pk[g] = pkbf2(a, b2);
            }
            u32 xa = sx32(hi ? pk[0] : pk[2]);
            u32 xb = sx32(hi ? pk[1] : pk[3]);
            u32 xc = sx32(hi ? pk[4] : pk[6]);
            u32 xd = sx32(hi ? pk[5] : pk[7]);
            pah0 = hi ? mk8(xa, xb, pk[2], pk[3]) : mk8(pk[0], pk[1], xa, xb);
            pah1 = hi ? mk8(xc, xd, pk[6], pk[7]) : mk8(pk[4], pk[5], xc, xd);
        }

        // ---- mid: drain V(t) just before PV ----
        if (t < 14) asm volatile("s_waitcnt vmcnt(4)" ::: "memory");
        else        asm volatile("s_waitcnt vmcnt(0)" ::: "memory");
        __builtin_amdgcn_sched_barrier(0);

        // ---- PV: bv read once, used for both q-groups ----
        __builtin_amdgcn_s_setprio(1);
#pragma unroll
        for (int ksg = 0; ksg < 2; ksg++) {
            const int off = ((ksg * 2 + hi) ^ vkey) << 3;
            s16x8 bv0 = *(const s16x8*)&Vq[l31 * 32 + off];
            s16x8 bv1 = *(const s16x8*)&Vq[(32 + l31) * 32 + off];
            s16x8 pl = ksg ? pal1 : pal0;
            s16x8 ph = ksg ? pah1 : pah0;
            aL0 = __builtin_amdgcn_mfma_f32_32x32x16_bf16(pl, bv0, aL0, 0, 0, 0);
            aL1 = __builtin_amdgcn_mfma_f32_32x32x16_bf16(pl, bv1, aL1, 0, 0, 0);
            aH0 = __builtin_amdgcn_mfma_f32_32x32x16_bf16(ph, bv0, aH0, 0, 0, 0);
            aH1 = __builtin_amdgcn_mfma_f32_32x32x16_bf16(ph, bv1, aH1, 0, 0, 0);
        }
        __builtin_amdgcn_s_setprio(0);
        __builtin_amdgcn_sched_barrier(0);

        // ---- end: issue V(t+1) into the SAME V buffer ----
        if (t < 15) {
            const u16* vp = vptr + (t + 1) * 32;
#pragma unroll
            for (int i = 0; i < 4; i++)
                gll16(vp + (size_t)(i * 16) * 2048, Vq + i * 512);
            sl = nl; sh = nh;
        }
    }

    // ---- per-q L across halves ----
    float Lsl = (lvl[0] + lvl[1]) + (lvl[2] + lvl[3]);
    Lsl += __shfl_xor(Lsl, 32, 64);
    float Lsh = (lvh[0] + lvh[1]) + (lvh[2] + lvh[3]);
    Lsh += __shfl_xor(Lsh, 32, 64);
    if (lane < 32) { Lbuf[w][l31] = Lsl; Lbuf[w][32 + l31] = Lsh; }

    // ---- two-pass 4-way merge (Obuf = 4 warps x 2048 floats = 32KB) ----
    float* Obuf = (float*)SMEM;
    const int lx = (lane & 7) * 4;
    const int ob = w * 2048 + lane * 32;
    const int eh = w & 1, gg = w >> 1;
    __syncthreads();

    // pass 1: q-group 0
#pragma unroll
    for (int g = 0; g < 4; g++) {
        *(f32x4*)&Obuf[ob + ((4 * g) ^ lx)] =
            (f32x4){aL0[4 * g], aL0[4 * g + 1], aL0[4 * g + 2], aL0[4 * g + 3]};
        *(f32x4*)&Obuf[ob + ((16 + 4 * g) ^ lx)] =
            (f32x4){aL1[4 * g], aL1[4 * g + 1], aL1[4 * g + 2], aL1[4 * g + 3]};
    }
    __syncthreads();
#pragma unroll
    for (int gi = 0; gi < 2; gi++) {
        const int g = gg * 2 + gi;
        const int off = (16 * eh + 4 * g) ^ lx;
        f32x4 s0 = *(const f32x4*)&Obuf[lane * 32 + off];
        f32x4 s1 = *(const f32x4*)&Obuf[2048 + lane * 32 + off];
        f32x4 s2 = *(const f32x4*)&Obuf[4096 + lane * 32 + off];
        f32x4 s3 = *(const f32x4*)&Obuf[6144 + lane * 32 + off];
        f32x4 sum = (s0 + s1) + (s2 + s3);
#pragma unroll
        for (int j = 0; j < 4; j++) {
            const int q = j + 4 * hi + 8 * g;
            float D = Lbuf[0][q] + Lbuf[1][q] + Lbuf[2][q] + Lbuf[3][q];
            const size_t orow = ((size_t)b * 2048 + qt * 64 + q) * 512 + h * 64 + eh * 32;
            oc[orow + l31] = f2b(sum[j] / D);
        }
    }
    __syncthreads();

    // pass 2: q-group 1
#pragma unroll
    for (int g = 0; g < 4; g++) {
        *(f32x4*)&Obuf[ob + ((4 * g) ^ lx)] =
            (f32x4){aH0[4 * g], aH0[4 * g + 1], aH0[4 * g + 2], aH0[4 * g + 3]};
        *(f32x4*)&Obuf[ob + ((16 + 4 * g) ^ lx)] =
            (f32x4){aH1[4 * g], aH1[4 * g + 1], aH1[4 * g + 2], aH1[4 * g + 3]};
    }
    __syncthreads();
#pragma unroll
    for (int gi = 0; gi < 2; gi++) {
        const int g = gg * 2 + gi;
        const int off = (16 * eh + 4 * g) ^ lx;
        f32x4 s0 = *(const f32x4*)&Obuf[lane * 32 + off];
        f32x4 s1 = *(const f32x4*)&Obuf[2048 + lane * 32 + off];
        f32x4 s2 = *(const f32x4*)&Obuf[4096 + lane * 32 + off];
        f32x4 s3 = *(const f32x4*)&Obuf[6144 + lane * 32 + off];
        f32x4 sum = (s0 + s1) + (s2 + s3);
#pragma unroll
        for (int j = 0; j < 4; j++) {
            const int q = j + 4 * hi + 8 * g;
            float D = Lbuf[0][32 + q] + Lbuf[1][32 + q] + Lbuf[2][32 + q] + Lbuf[3][32 + q];
            const size_t orow = ((size_t)b * 2048 + qt * 64 + 32 + q) * 512 + h * 64 + eh * 32;
            oc[orow + l31] = f2b(sum[j] / D);
        }
    }
}

// ---------------- launcher ----------------

extern "C" void kernel_launch(void* const* d_in, const int* in_sizes, int n_in,
                              void* d_out, int out_size, void* d_ws, size_t ws_size,
                              hipStream_t stream) {
    const float* x    = (const float*)d_in[0];
    const int*   mask = (const int*)d_in[1];
    const float* Wq   = (const float*)d_in[2];
    const float* bq   = (const float*)d_in[3];
    const float* Wk   = (const float*)d_in[4];
    const float* bk   = (const float*)d_in[5];
    const float* Wv   = (const float*)d_in[6];
    const float* bv   = (const float*)d_in[7];
    const float* Wo   = (const float*)d_in[8];
    const float* bo   = (const float*)d_in[9];

    u16* xb     = (u16*)d_ws;              // 2097152 bf16
    u16* WT     = xb + 2097152;            // 3*262144
    u16* WoT    = WT + 786432;             // 262144
    u16* qkv    = WoT + 262144;            // Q,K: 2*2097152
    u16* vtp    = qkv + 4194304;           // 2097152 (vt[b][he][s])
    u16* oc     = qkv + 6291456;           // 2097152
    float* bias = (float*)(oc + 2097152);  // 2048 floats
    u32* mbits  = (u32*)(bias + 2048);     // 262144 words (1 MB)

    k_pack_all<<<6152, 256, 0, stream>>>(x, Wq, Wk, Wv, Wo, bq, bk, bv, bo,
                                         xb, WT, WoT, bias);
    k_gemm<2, false><<<dim3(4, 64, 4), 256, 0, stream>>>(
        xb, WT, bias, qkv, vtp, nullptr, mask, mbits);
    k_attn<<<dim3(32, 8, 2), 256, 0, stream>>>(qkv, vtp, mbits, oc);
    k_gemm<1, true><<<dim3(4, 128, 1), 256, 0, stream>>>(
        oc, WoT, bias + 1536, nullptr, nullptr, (float*)d_out, nullptr, nullptr);
}